// Round 2
// baseline (589.415 us; speedup 1.0000x reference)
//
#include <hip/hip_runtime.h>
#include <hip/hip_bf16.h>
#include <math.h>

// Problem constants
#define NPIX 102400          // B*H*W
#define NSEED 4
#define RTOT (NPIX * NSEED)  // 409600 rows
#define GG 8
#define DD 64
#define EE 128
#define BM 64                // rows per block (16 pixels x 4 seeds), 16 rows per wave

// Padded K dims (multiples of 32 for 16x16x32 MFMA)
#define KP1 96               // 72 -> 96
#define KP2 128
#define KP3 160              // 159 -> 160

// Per-wave LDS slice row stride (shorts). 168 shorts = 84 dw; 16-lane read
// stride 84 dw mod 32 = 20 -> 8 distinct start banks x 4 banks covers all 32,
// 2 lanes/bank = free (m136).
#define PS 168

typedef short bf16x8 __attribute__((ext_vector_type(8)));
typedef short bf16x4 __attribute__((ext_vector_type(4)));
typedef float f32x4 __attribute__((ext_vector_type(4)));

static __device__ __forceinline__ short f2bf(float x) {
    __hip_bfloat16 h = __float2bfloat16(x);  // RNE
    return __builtin_bit_cast(short, h);
}

// Fast gelu: Phi via Abramowitz-Stegun 7.1.26 erf (|err| < 1.5e-7), using
// hw v_rcp/v_exp. Error is ~1e-6*|x| -- far below the bf16 cast of h.
static __device__ __forceinline__ float gelu_fast(float x) {
    const float z = fabsf(x) * 0.7071067811865475f;
    const float t = __builtin_amdgcn_rcpf(__builtin_fmaf(0.3275911f, z, 1.0f));
    float p = __builtin_fmaf(1.061405429f, t, -1.453152027f);
    p = __builtin_fmaf(p, t, 1.421413741f);
    p = __builtin_fmaf(p, t, -0.284496736f);
    p = __builtin_fmaf(p, t, 0.254829592f);
    p = p * t;
    const float e = __expf(-z * z);          // native v_exp path
    const float q = 0.5f * p * e;            // Phi(-|x|)
    const float phi = (x >= 0.0f) ? (1.0f - q) : q;
    return x * phi;
}

// ---- pre-pass: transpose + bf16-cast weights, and build fourier LUT ----
// ws layout (shorts): W1T [128][96] @0 | W2T [128][128] @12288 |
//                     WpT [128][160] @28672 | Ftab [64][32] @49152
// total 51200 shorts = 100 KB
__global__ void prep_weights(const float* __restrict__ W1,
                             const float* __restrict__ W2,
                             const float* __restrict__ Wp,
                             short* __restrict__ ws) {
    const int i = blockIdx.x * 256 + threadIdx.x;  // grid covers 51200
    if (i < 12288) {
        const int e = i / KP1, k = i - e * KP1;
        ws[i] = (k < 72) ? f2bf(W1[k * EE + e]) : (short)0;
    } else if (i < 12288 + 16384) {
        const int j = i - 12288;
        const int e = j / KP2, k = j - e * KP2;
        ws[i] = f2bf(W2[k * EE + e]);
    } else if (i < 49152) {
        const int j = i - 28672;
        const int e = j / KP3, k = j - e * KP3;
        ws[i] = (k < 159) ? f2bf(Wp[k * EE + e]) : (short)0;
    } else if (i < 51200) {
        // fourier LUT: label values are integers 0..63 -> only 64 rows.
        const int j = i - 49152;
        const int sd = j >> 5, c = j & 31;
        const float coord = (float)sd * (float)(3.14 / 64.0);
        float v;
        if (c < 15) v = sinf(coord * (float)(1 << c));
        else if (c < 30) v = cosf(coord * (float)(1 << (c - 15)));
        else if (c == 30) v = coord;
        else v = 0.0f;  // k=159 pad
        ws[i] = f2bf(v);
    }
}

// One stage: acc[m] += W^T(m-tile, all k) x act^T(16 rows). A from global
// (L1/L2-hot weights), B from this wave's private LDS slice. N-tile = 16 rows.
template <int KPAD>
__device__ __forceinline__ void gemm_w(const short* __restrict__ WT, const short* sB,
                                       int ln, int qd, f32x4 acc[8]) {
#pragma unroll
    for (int ks = 0; ks < KPAD / 32; ++ks) {
        const int kb = ks * 32 + qd * 8;
        const bf16x8 b = *(const bf16x8*)(sB + ln * PS + kb);
#pragma unroll
        for (int m = 0; m < 8; ++m) {
            const bf16x8 a = *(const bf16x8*)(WT + (m * 16 + ln) * KPAD + kb);
            acc[m] = __builtin_amdgcn_mfma_f32_16x16x32_bf16(a, b, acc[m], 0, 0, 0);
        }
    }
}

// Barrier-free: each wave owns 16 rows end-to-end in a private LDS slice.
// Same-wave DS ops are processed in order by the LDS unit; the empty-asm
// memory fences pin compiler instruction order at phase boundaries.
// LDS 21504 B -> 7 blocks/CU; launch_bounds(.,6) caps VGPR at 85.
__global__ __launch_bounds__(256, 6)
void Propagation_85315230368231_kernel(const float* __restrict__ cost_volume,
                                       const int* __restrict__ label_seed,
                                       const short* __restrict__ ws,
                                       const float* __restrict__ b1,
                                       const float* __restrict__ b2,
                                       float* __restrict__ out) {
    __shared__ short sU[4 * 16 * PS];  // 4 private wave slices, 21504 B

    const short* W1T = ws;
    const short* W2T = ws + 12288;
    const short* WpT = ws + 28672;
    const short* Ftab = ws + 49152;

    const int tid = threadIdx.x;
    const int wave = tid >> 6;
    const int lane = tid & 63;
    const int ln = lane & 15;
    const int qd = lane >> 4;
    const int blk = blockIdx.x;
    const int row0 = blk * BM;
    const int wrow0 = row0 + wave * 16;            // first global row of wave
    const int wp0 = blk * (BM / NSEED) + wave * 4; // first pixel of wave
    short* sW = sU + wave * 16 * PS;               // private slice

    if (tid < BM) {
        out[(size_t)RTOT * EE + row0 + tid] = (float)label_seed[row0 + tid];
    }

    // ---- gather cost -> sW cols [0,72). One (row,group) pair per item:
    // 9 contiguous scattered loads, clamp via med3, bf16 scalar LDS writes.
#pragma unroll
    for (int i = 0; i < 2; ++i) {
        const int item = lane + i * 64;
        const int r = item >> 3;
        const int g = item & 7;
        const int sd = label_seed[wrow0 + r];
        const float* cv = cost_volume + (size_t)(wp0 + (r >> 2)) * (GG * DD) + g * DD;
        const int dbase = sd - 4;
        float v[9];
#pragma unroll
        for (int c = 0; c < 9; ++c) {
            int d = dbase + c;
            d = d < 0 ? 0 : d;
            d = d > 63 ? 63 : d;
            v[c] = cv[d];
        }
        short* dst = sW + r * PS + g * 9;
#pragma unroll
        for (int c = 0; c < 9; ++c) dst[c] = f2bf(v[c]);
    }
    // zero-pad cols [72,96): 16 rows x 3 x 16B chunks = 48 writes
    if (lane < 48) {
        const int r = lane / 3;
        const int j = lane - 3 * r;
        *(bf16x8*)(sW + r * PS + 72 + j * 8) = (bf16x8)0;
    }
    // fourier cols [128,160) from LUT: one 16B load + one 16B LDS write each
    {
        const int r = lane >> 2, ch = lane & 3;
        const int sd = label_seed[wrow0 + r];
        const bf16x8 t = *(const bf16x8*)(Ftab + sd * 32 + ch * 8);
        *(bf16x8*)(sW + r * PS + 128 + ch * 8) = t;
    }
    asm volatile("" ::: "memory");  // gather/pad/fourier before stage-1 reads

    f32x4 acc[8];

    // ---- stage 1: h^T = gelu(W1T x cost^T + b1) -> sW cols [0,128) ----
#pragma unroll
    for (int m = 0; m < 8; ++m) acc[m] = (f32x4)0.0f;
    gemm_w<KP1>(W1T, sW, ln, qd, acc);
    asm volatile("" ::: "memory");  // stage-1 reads before h writes
#pragma unroll
    for (int m = 0; m < 8; ++m) {
        const int eb = m * 16 + qd * 4;
        const float4 bv = *(const float4*)(b1 + eb);
        bf16x4 p;
        p[0] = f2bf(gelu_fast(acc[m][0] + bv.x));
        p[1] = f2bf(gelu_fast(acc[m][1] + bv.y));
        p[2] = f2bf(gelu_fast(acc[m][2] + bv.z));
        p[3] = f2bf(gelu_fast(acc[m][3] + bv.w));
        *(bf16x4*)(sW + ln * PS + eb) = p;
    }
    asm volatile("" ::: "memory");  // h writes before stage-2 reads

    // ---- stage 2: F^T = W2T x h^T + b2 -> sW cols [0,128) ----
#pragma unroll
    for (int m = 0; m < 8; ++m) acc[m] = (f32x4)0.0f;
    gemm_w<KP2>(W2T, sW, ln, qd, acc);
    asm volatile("" ::: "memory");  // stage-2 reads before F writes
#pragma unroll
    for (int m = 0; m < 8; ++m) {
        const int eb = m * 16 + qd * 4;
        const float4 bv = *(const float4*)(b2 + eb);
        bf16x4 p;
        p[0] = f2bf(acc[m][0] + bv.x);
        p[1] = f2bf(acc[m][1] + bv.y);
        p[2] = f2bf(acc[m][2] + bv.z);
        p[3] = f2bf(acc[m][3] + bv.w);
        *(bf16x4*)(sW + ln * PS + eb) = p;
    }
    asm volatile("" ::: "memory");  // F writes before stage-3 reads

    // ---- stage 3: out^T = WpT x [F|disp]^T ----
#pragma unroll
    for (int m = 0; m < 8; ++m) acc[m] = (f32x4)0.0f;
    gemm_w<KP3>(WpT, sW, ln, qd, acc);
#pragma unroll
    for (int m = 0; m < 8; ++m) {
        const int eb = m * 16 + qd * 4;
        const size_t grow = (size_t)(wrow0 + ln);
        float4 v = {acc[m][0], acc[m][1], acc[m][2], acc[m][3]};
        *(float4*)(out + grow * EE + eb) = v;
    }
}

extern "C" void kernel_launch(void* const* d_in, const int* in_sizes, int n_in,
                              void* d_out, int out_size, void* d_ws, size_t ws_size,
                              hipStream_t stream) {
    const float* cost_volume = (const float*)d_in[0];
    const int* label_seed = (const int*)d_in[1];
    // d_in[2] = context: unused (layers=[], norm=None)
    const float* W1 = (const float*)d_in[3];
    const float* b1 = (const float*)d_in[4];
    const float* W2 = (const float*)d_in[5];
    const float* b2 = (const float*)d_in[6];
    const float* Wp = (const float*)d_in[7];
    float* out = (float*)d_out;
    short* ws = (short*)d_ws;  // needs 51200 shorts = 100 KB

    prep_weights<<<200, 256, 0, stream>>>(W1, W2, Wp, ws);
    Propagation_85315230368231_kernel<<<RTOT / BM, 256, 0, stream>>>(
        cost_volume, label_seed, ws, b1, b2, out);
}